// Round 1
// baseline (230.874 us; speedup 1.0000x reference)
//
#include <hip/hip_runtime.h>

constexpr int HW = 1024 * 1024;
constexpr int NB = 16;
constexpr float EPS = 1e-6f;
constexpr int BLOCKS_PER_BATCH = 128;  // 2048 blocks total -> 8 blocks/CU
constexpr int THREADS = 256;
constexpr int NVEC    = HW / 4;                      // 262144 vec4 per batch
constexpr int U       = NVEC / (BLOCKS_PER_BATCH * THREADS);  // 8 windows/thread
constexpr int CHUNK   = THREADS * U;                 // 2048 vec4 = 32 KB per block per stream
constexpr int NBLK    = NB * BLOCKS_PER_BATCH;       // 2048

typedef float f32x4 __attribute__((ext_vector_type(4)));
typedef int   i32x4 __attribute__((ext_vector_type(4)));

// Stage 1: per-block partials -> ws4[gid] = {Sp, Spp, St, Stp}. No atomics.
// Block-contiguous layout: each block streams a contiguous 32 KB chunk from
// each of the three input streams (window stride = 4 KB), instead of the
// previous whole-batch interleave (window stride = 512 KB). Plain (cached)
// loads — the nt hint bought nothing (inputs are evicted by the harness's
// 512 MiB poison fills between iterations) and the 6.3 TB/s ceiling was
// measured with plain float4 loads.
__global__ __launch_bounds__(THREADS, 8) void dice_partial(
        const float* __restrict__ logits,
        const int*   __restrict__ labels,
        f32x4*       __restrict__ ws4) {
    const int b   = blockIdx.x >> 7;         // / BLOCKS_PER_BATCH
    const int blk = blockIdx.x & 127;        // % BLOCKS_PER_BATCH

    const f32x4* __restrict__ L0 = reinterpret_cast<const f32x4*>(logits + (size_t)b * 2 * HW);
    const f32x4* __restrict__ L1 = reinterpret_cast<const f32x4*>(logits + (size_t)b * 2 * HW + HW);
    const i32x4* __restrict__ LB = reinterpret_cast<const i32x4*>(labels + (size_t)b * HW);

    const int base = blk * CHUNK + threadIdx.x;   // contiguous chunk per block

    f32x4 a[2], c[2];
    i32x4 t[2];
    a[0] = L0[base];
    c[0] = L1[base];
    t[0] = LB[base];
    a[1] = L0[base + THREADS];
    c[1] = L1[base + THREADS];
    t[1] = LB[base + THREADS];

    float sp = 0.f, spp = 0.f, st = 0.f, stp = 0.f;

    #pragma unroll
    for (int u = 0; u < U; ++u) {
        const int cur = u & 1;
        f32x4 an, cn;
        i32x4 tn;
        const bool pf = (u + 2 < U);
        if (pf) {
            const int i = base + (u + 2) * THREADS;
            an = L0[i];
            cn = L1[i];
            tn = LB[i];
        }
        #pragma unroll
        for (int k = 0; k < 4; ++k) {
            const float p  = 1.f / (1.f + __expf(a[cur][k] - c[cur][k]));
            const float tf = (float)t[cur][k];
            sp += p; spp = fmaf(p, p, spp); st += tf; stp = fmaf(tf, p, stp);
        }
        if (pf) { a[cur] = an; c[cur] = cn; t[cur] = tn; }
    }

    // wave-64 shuffle reduction
    #pragma unroll
    for (int off = 32; off > 0; off >>= 1) {
        sp  += __shfl_down(sp,  off);
        spp += __shfl_down(spp, off);
        st  += __shfl_down(st,  off);
        stp += __shfl_down(stp, off);
    }

    __shared__ float red[4][4];   // [wave][component]
    const int wave = threadIdx.x >> 6;
    const int lane = threadIdx.x & 63;
    if (lane == 0) {
        red[wave][0] = sp; red[wave][1] = spp; red[wave][2] = st; red[wave][3] = stp;
    }
    __syncthreads();
    if (threadIdx.x == 0) {
        f32x4 r;
        r.x = red[0][0] + red[1][0] + red[2][0] + red[3][0];
        r.y = red[0][1] + red[1][1] + red[2][1] + red[3][1];
        r.z = red[0][2] + red[1][2] + red[2][2] + red[3][2];
        r.w = red[0][3] + red[1][3] + red[2][3] + red[3][3];
        ws4[blockIdx.x] = r;   // plain store, distinct slot per block
    }
}

// Stage 2 (merged): one block, 1024 threads = 16 waves; wave w folds batch w's
// 128 partials and computes its dice term; wave 0 then folds the 16 terms.
__global__ __launch_bounds__(1024) void dice_reduce(
        const f32x4* __restrict__ ws4,
        float*       __restrict__ out) {
    const int wave = threadIdx.x >> 6;   // 0..15 == batch index
    const int lane = threadIdx.x & 63;

    f32x4 v = ws4[wave * BLOCKS_PER_BATCH + lane]
            + ws4[wave * BLOCKS_PER_BATCH + 64 + lane];

    #pragma unroll
    for (int off = 32; off > 0; off >>= 1) {
        v.x += __shfl_down(v.x, off);
        v.y += __shfl_down(v.y, off);
        v.z += __shfl_down(v.z, off);
        v.w += __shfl_down(v.w, off);
    }

    __shared__ float terms[NB];
    if (lane == 0) {
        const float Sp  = v.x;
        const float Spp = v.y;
        const float St  = v.z;
        const float Stp = v.w;
        const float N = (float)HW;

        const float num1 = 2.f * Stp;
        const float den1 = Spp + St;
        const float num0 = 2.f * (N - St - Sp + Stp);
        const float den0 = (N - 2.f * Sp + Spp) + (N - St);

        terms[wave] = num0 / (den0 + EPS) + num1 / (den1 + EPS);
    }
    __syncthreads();
    if (threadIdx.x == 0) {
        float s = 0.f;
        #pragma unroll
        for (int i = 0; i < NB; ++i) s += terms[i];
        out[0] = 1.f - s / 32.f;
    }
}

extern "C" void kernel_launch(void* const* d_in, const int* in_sizes, int n_in,
                              void* d_out, int out_size, void* d_ws, size_t ws_size,
                              hipStream_t stream) {
    const float* logits = (const float*)d_in[0];
    const int*   labels = (const int*)d_in[1];
    float* out = (float*)d_out;
    f32x4* ws4 = (f32x4*)d_ws;                       // 2048 vec4 = 32 KB

    dice_partial<<<NBLK, THREADS, 0, stream>>>(logits, labels, ws4);
    dice_reduce<<<1, 1024, 0, stream>>>(ws4, out);
}

// Round 2
// 214.704 us; speedup vs baseline: 1.0753x; 1.0753x over previous
//
#include <hip/hip_runtime.h>

constexpr int HW = 1024 * 1024;
constexpr int NB = 16;
constexpr float EPS = 1e-6f;
constexpr int BLOCKS_PER_BATCH = 256;  // 4096 blocks total
constexpr int THREADS = 256;
constexpr int NVEC    = HW / 4;                      // 262144 vec4 per batch
constexpr int TPB     = BLOCKS_PER_BATCH * THREADS;  // 65536 threads per batch
constexpr int U       = NVEC / TPB;                  // 4 windows per thread (exact)
constexpr int NBLK    = NB * BLOCKS_PER_BATCH;       // 4096

typedef float f32x4 __attribute__((ext_vector_type(4)));
typedef int   i32x4 __attribute__((ext_vector_type(4)));

// Stage 1: per-block partials -> ws4[gid] = {Sp, Spp, St, Stp}. No atomics.
//
// Deep-pipeline version: ALL 12 nt-loads (4 windows x 3 streams) are issued
// up front into distinct registers, then a sched_barrier(0) pins them there
// (round 1 showed VGPR_Count=32: the compiler had sunk the "prefetch" loads
// back to their uses, leaving ~3 loads in flight per wave -> 2.6 TB/s
// latency-limited). 12 loads/wave x ~24-32 waves/CU = ~300 KB/CU in flight.
__global__ __launch_bounds__(THREADS, 6) void dice_partial(
        const float* __restrict__ logits,
        const int*   __restrict__ labels,
        f32x4*       __restrict__ ws4) {
    const int b   = blockIdx.x >> 8;         // / BLOCKS_PER_BATCH
    const int blk = blockIdx.x & 255;        // % BLOCKS_PER_BATCH

    const f32x4* __restrict__ L0 = reinterpret_cast<const f32x4*>(logits + (size_t)b * 2 * HW);
    const f32x4* __restrict__ L1 = reinterpret_cast<const f32x4*>(logits + (size_t)b * 2 * HW + HW);
    const i32x4* __restrict__ LB = reinterpret_cast<const i32x4*>(labels + (size_t)b * HW);

    const int base = blk * THREADS + threadIdx.x;   // interleaved, window stride = TPB

    // Issue all 12 loads, window-major, so consumption of window u can
    // proceed at vmcnt(9/6/3/0) while later windows stay in flight.
    f32x4 a0 = __builtin_nontemporal_load(&L0[base + 0 * TPB]);
    f32x4 c0 = __builtin_nontemporal_load(&L1[base + 0 * TPB]);
    i32x4 t0 = __builtin_nontemporal_load(&LB[base + 0 * TPB]);
    f32x4 a1 = __builtin_nontemporal_load(&L0[base + 1 * TPB]);
    f32x4 c1 = __builtin_nontemporal_load(&L1[base + 1 * TPB]);
    i32x4 t1 = __builtin_nontemporal_load(&LB[base + 1 * TPB]);
    f32x4 a2 = __builtin_nontemporal_load(&L0[base + 2 * TPB]);
    f32x4 c2 = __builtin_nontemporal_load(&L1[base + 2 * TPB]);
    i32x4 t2 = __builtin_nontemporal_load(&LB[base + 2 * TPB]);
    f32x4 a3 = __builtin_nontemporal_load(&L0[base + 3 * TPB]);
    f32x4 c3 = __builtin_nontemporal_load(&L1[base + 3 * TPB]);
    i32x4 t3 = __builtin_nontemporal_load(&LB[base + 3 * TPB]);
    __builtin_amdgcn_sched_barrier(0);   // loads may not sink past this point

    float sp = 0.f, spp = 0.f, st = 0.f, stp = 0.f;

    #define CONSUME(A, C, T)                                              \
        _Pragma("unroll")                                                 \
        for (int k = 0; k < 4; ++k) {                                     \
            const float p  = 1.f / (1.f + __expf((A)[k] - (C)[k]));       \
            const float tf = (float)(T)[k];                               \
            sp += p; spp = fmaf(p, p, spp); st += tf; stp = fmaf(tf, p, stp); \
        }

    CONSUME(a0, c0, t0)
    CONSUME(a1, c1, t1)
    CONSUME(a2, c2, t2)
    CONSUME(a3, c3, t3)
    #undef CONSUME

    // wave-64 shuffle reduction
    #pragma unroll
    for (int off = 32; off > 0; off >>= 1) {
        sp  += __shfl_down(sp,  off);
        spp += __shfl_down(spp, off);
        st  += __shfl_down(st,  off);
        stp += __shfl_down(stp, off);
    }

    __shared__ float red[4][4];   // [wave][component]
    const int wave = threadIdx.x >> 6;
    const int lane = threadIdx.x & 63;
    if (lane == 0) {
        red[wave][0] = sp; red[wave][1] = spp; red[wave][2] = st; red[wave][3] = stp;
    }
    __syncthreads();
    if (threadIdx.x == 0) {
        f32x4 r;
        r.x = red[0][0] + red[1][0] + red[2][0] + red[3][0];
        r.y = red[0][1] + red[1][1] + red[2][1] + red[3][1];
        r.z = red[0][2] + red[1][2] + red[2][2] + red[3][2];
        r.w = red[0][3] + red[1][3] + red[2][3] + red[3][3];
        ws4[blockIdx.x] = r;   // plain store, distinct slot per block
    }
}

// Stage 2 (merged): one block, 1024 threads = 16 waves; wave w folds batch w's
// 256 partials and computes its dice term; thread 0 then folds the 16 terms.
__global__ __launch_bounds__(1024) void dice_reduce(
        const f32x4* __restrict__ ws4,
        float*       __restrict__ out) {
    const int wave = threadIdx.x >> 6;   // 0..15 == batch index
    const int lane = threadIdx.x & 63;

    const f32x4* p = ws4 + wave * BLOCKS_PER_BATCH;
    f32x4 v = p[lane] + p[lane + 64] + p[lane + 128] + p[lane + 192];

    #pragma unroll
    for (int off = 32; off > 0; off >>= 1) {
        v.x += __shfl_down(v.x, off);
        v.y += __shfl_down(v.y, off);
        v.z += __shfl_down(v.z, off);
        v.w += __shfl_down(v.w, off);
    }

    __shared__ float terms[NB];
    if (lane == 0) {
        const float Sp  = v.x;
        const float Spp = v.y;
        const float St  = v.z;
        const float Stp = v.w;
        const float N = (float)HW;

        const float num1 = 2.f * Stp;
        const float den1 = Spp + St;
        const float num0 = 2.f * (N - St - Sp + Stp);
        const float den0 = (N - 2.f * Sp + Spp) + (N - St);

        terms[wave] = num0 / (den0 + EPS) + num1 / (den1 + EPS);
    }
    __syncthreads();
    if (threadIdx.x == 0) {
        float s = 0.f;
        #pragma unroll
        for (int i = 0; i < NB; ++i) s += terms[i];
        out[0] = 1.f - s / 32.f;
    }
}

extern "C" void kernel_launch(void* const* d_in, const int* in_sizes, int n_in,
                              void* d_out, int out_size, void* d_ws, size_t ws_size,
                              hipStream_t stream) {
    const float* logits = (const float*)d_in[0];
    const int*   labels = (const int*)d_in[1];
    float* out = (float*)d_out;
    f32x4* ws4 = (f32x4*)d_ws;                       // 4096 vec4 = 64 KB

    dice_partial<<<NBLK, THREADS, 0, stream>>>(logits, labels, ws4);
    dice_reduce<<<1, 1024, 0, stream>>>(ws4, out);
}